// Round 3
// baseline (1229.810 us; speedup 1.0000x reference)
//
#include <hip/hip_runtime.h>
#include <stdint.h>

#define NN 50000
#define NE 800000
#define NP 50048   // 391*128, padded row count for 128-row gemm tiles

typedef _Float16 f16x8 __attribute__((ext_vector_type(8)));
typedef float f32x4 __attribute__((ext_vector_type(4)));

__device__ __forceinline__ float h2f(unsigned short u){
  union { unsigned short u; _Float16 h; } x; x.u = u; return (float)x.h;
}
__device__ __forceinline__ unsigned short f2h(float f){
  union { _Float16 h; unsigned short u; } x; x.h = (_Float16)f; return x.u;  // v_cvt_f16_f32, RNE
}
__device__ __forceinline__ void load_lds16(const void* g, void* l){
  __builtin_amdgcn_global_load_lds((const __attribute__((address_space(1))) void*)g,
                                   (__attribute__((address_space(3))) void*)l, 16, 0, 0);
}

// ---------------- fp32 -> fp16 cast (vectorized) ----------------
__global__ void k_cast(const float* __restrict__ src, unsigned short* __restrict__ dst, int n4){
  int i = blockIdx.x*blockDim.x + threadIdx.x;
  if (i >= n4) return;
  float4 v = ((const float4*)src)[i];
  uint2 o;
  o.x = (unsigned int)f2h(v.x) | ((unsigned int)f2h(v.y) << 16);
  o.y = (unsigned int)f2h(v.z) | ((unsigned int)f2h(v.w) << 16);
  ((uint2*)dst)[i] = o;
}

// ---------------- CSR build ----------------
__global__ void k_hist(const int* __restrict__ rows, int* __restrict__ cnt){
  int e = blockIdx.x*blockDim.x + threadIdx.x;
  if (e < NE) atomicAdd(&cnt[rows[e]], 1);
}

__global__ __launch_bounds__(1024) void k_scan(const int* __restrict__ cnt, int* __restrict__ rowptr){
  __shared__ int sh[1024];
  const int T = 1024, CH = (NN + T - 1) / T;  // 49
  int t = threadIdx.x;
  int base = t * CH;
  int local = 0;
  for (int i = 0; i < CH; i++){ int idx = base + i; if (idx < NN) local += cnt[idx]; }
  sh[t] = local; __syncthreads();
  for (int off = 1; off < T; off <<= 1){
    int v = (t >= off) ? sh[t - off] : 0;
    __syncthreads();
    sh[t] += v;
    __syncthreads();
  }
  int run = (t == 0) ? 0 : sh[t - 1];
  for (int i = 0; i < CH; i++){
    int idx = base + i;
    if (idx < NN){ rowptr[idx] = run; run += cnt[idx]; }
    else if (idx == NN){ rowptr[idx] = run; }
  }
}

__global__ void k_scatter(const int* __restrict__ rows, const int* __restrict__ cols,
                          const float* __restrict__ vals,
                          const int* __restrict__ rowptr, int* __restrict__ fill,
                          int* __restrict__ colss, float* __restrict__ valss){
  int e = blockIdx.x*blockDim.x + threadIdx.x;
  if (e >= NE) return;
  int r = rows[e];
  int p = rowptr[r] + atomicAdd(&fill[r], 1);
  colss[p] = cols[e];
  valss[p] = vals[e];
}

// ---------------- weight concat: WT[j][k], j=out col (alpha 0-127 | beta 128-255), k in 4*Fin ----------------
__global__ void k_buildWT(const float* __restrict__ Wa, const float* __restrict__ Wb,
                          unsigned short* __restrict__ WT, int Fin){
  int Ktot = 4 * Fin;
  int idx = blockIdx.x*blockDim.x + threadIdx.x;
  if (idx >= 256 * Ktot) return;
  int j = idx / Ktot, k = idx - j * Ktot;
  int seg = k / Fin, ki = k - seg * Fin;
  const float* W = (j < 128) ? Wa : Wb;
  int jj = (j < 128) ? j : j - 128;
  int stride = Fin * 128;
  float v;
  if (seg == 0)
    v = W[0*stride + ki*128 + jj] + W[1*stride + ki*128 + jj] + W[2*stride + ki*128 + jj];
  else
    v = W[(seg + 2)*stride + ki*128 + jj];
  WT[j*Ktot + k] = f2h(v);
}

// ---------------- SpMM: one wave per row, fp32 accumulate, fp16 in/out ----------------
template<int F>
__global__ void k_spmm(const int* __restrict__ rowptr, const int* __restrict__ colss,
                       const float* __restrict__ valss,
                       const unsigned short* __restrict__ X, unsigned short* __restrict__ Y){
  int row = blockIdx.x * (blockDim.x >> 6) + (threadIdx.x >> 6);
  if (row >= NN) return;
  int lane = threadIdx.x & 63;
  constexpr int P = F / 64;        // 2 (F=128) or 4 (F=256) elems per lane
  float acc[P];
  #pragma unroll
  for (int i = 0; i < P; i++) acc[i] = 0.f;
  int s = rowptr[row], e = rowptr[row + 1];
  for (int i = s; i < e; i++){
    int c = colss[i];
    float v = valss[i];
    const unsigned short* src = X + (size_t)c * F + lane * P;
    if (P == 2){
      unsigned int u = *(const unsigned int*)src;
      acc[0] += v * h2f((unsigned short)u);
      acc[1] += v * h2f((unsigned short)(u >> 16));
    } else {
      uint2 u = *(const uint2*)src;
      acc[0] += v * h2f((unsigned short)u.x);
      acc[1] += v * h2f((unsigned short)(u.x >> 16));
      acc[2] += v * h2f((unsigned short)u.y);
      acc[3] += v * h2f((unsigned short)(u.y >> 16));
    }
  }
  unsigned short* dst = Y + (size_t)row * F + lane * P;
  if (P == 2){
    unsigned int o = (unsigned int)f2h(acc[0]) | ((unsigned int)f2h(acc[1]) << 16);
    *(unsigned int*)dst = o;
  } else {
    uint2 o;
    o.x = (unsigned int)f2h(acc[0]) | ((unsigned int)f2h(acc[1]) << 16);
    o.y = (unsigned int)f2h(acc[2]) | ((unsigned int)f2h(acc[3]) << 16);
    *(uint2*)dst = o;
  }
}

// ---------------- 4-source fused GEMM: C(N x 256) = [A0|A1|A2|A3](N x 4*FIN) @ WT^T ----------------
// m97 structure: 128x128 tile, BK=32, global_load_lds width 16, mfma_f32_16x16x32_f16.
template<int FIN>
__global__ __launch_bounds__(256) void k_gemm4(
    const unsigned short* __restrict__ A0, const unsigned short* __restrict__ A1,
    const unsigned short* __restrict__ A2, const unsigned short* __restrict__ A3,
    const unsigned short* __restrict__ BT, float* __restrict__ C){
  constexpr int KTOT = 4 * FIN;
  __shared__ unsigned short As[128 * 32];
  __shared__ unsigned short Bs[128 * 32];
  int tid = threadIdx.x, lane = tid & 63;
  int wm = (tid >> 6) & 1, wn = tid >> 7;
  int bm = blockIdx.x, bn = blockIdx.y;

  f32x4 acc[4][4];
  #pragma unroll
  for (int i = 0; i < 4; i++)
    #pragma unroll
    for (int j = 0; j < 4; j++) acc[i][j] = (f32x4){0.f, 0.f, 0.f, 0.f};

  // staging roles: thread t stages 16B at element offset t*8 (row t/4, kcol (t%4)*8); two calls cover 128 rows
  int ac = (tid & 3) * 8;
  int gr0 = bm * 128 + (tid >> 2);        if (gr0 >= NN) gr0 = NN - 1;   // clamp: pad rows read row NN-1, outputs discarded
  int gr1 = bm * 128 + ((256 + tid) >> 2); if (gr1 >= NN) gr1 = NN - 1;
  int br0 = (tid >> 2), br1 = ((256 + tid) >> 2);
  const unsigned short* Bb = BT + (size_t)(bn * 128) * KTOT;
  unsigned short* Adst0 = As + (size_t)(tid & ~63) * 8;
  unsigned short* Adst1 = As + (size_t)(256 + (tid & ~63)) * 8;
  unsigned short* Bdst0 = Bs + (size_t)(tid & ~63) * 8;
  unsigned short* Bdst1 = Bs + (size_t)(256 + (tid & ~63)) * 8;

  int m0 = wm * 64 + (lane & 15);
  int n0 = wn * 64 + (lane & 15);
  int qk = (lane >> 4) * 8;

  #pragma unroll
  for (int seg = 0; seg < 4; seg++){
    const unsigned short* Asrc = (seg == 0) ? A0 : (seg == 1) ? A1 : (seg == 2) ? A2 : A3;
    const unsigned short* Bseg = Bb + seg * FIN;
    for (int kl = 0; kl < FIN; kl += 32){
      load_lds16(Asrc + (size_t)gr0 * FIN + kl + ac, Adst0);
      load_lds16(Asrc + (size_t)gr1 * FIN + kl + ac, Adst1);
      load_lds16(Bseg + (size_t)br0 * KTOT + kl + ac, Bdst0);
      load_lds16(Bseg + (size_t)br1 * KTOT + kl + ac, Bdst1);
      __syncthreads();
      f16x8 af[4], bfr[4];
      #pragma unroll
      for (int i = 0; i < 4; i++) af[i]  = *(const f16x8*)(As + (m0 + i * 16) * 32 + qk);
      #pragma unroll
      for (int j = 0; j < 4; j++) bfr[j] = *(const f16x8*)(Bs + (n0 + j * 16) * 32 + qk);
      #pragma unroll
      for (int i = 0; i < 4; i++)
        #pragma unroll
        for (int j = 0; j < 4; j++)
          acc[i][j] = __builtin_amdgcn_mfma_f32_16x16x32_f16(af[i], bfr[j], acc[i][j], 0, 0, 0);
      __syncthreads();
    }
  }
  // epilogue: C/D layout col=lane&15, row=(lane>>4)*4+reg (m89/m91-verified, dtype-independent)
  int cn = bn * 128 + wn * 64 + (lane & 15);
  int rb = bm * 128 + wm * 64 + ((lane >> 4) << 2);
  #pragma unroll
  for (int i = 0; i < 4; i++)
    #pragma unroll
    for (int j = 0; j < 4; j++)
      #pragma unroll
      for (int g = 0; g < 4; g++){
        int rr = rb + i * 16 + g;
        if (rr < NN) C[(size_t)rr * 256 + cn + j * 16] = acc[i][j][g];
      }
}

// ---------------- BatchNorm (training-mode stats), relu-before-stats on alpha half ----------------
__global__ void k_bnstats(const float* __restrict__ H, float* __restrict__ stats){
  int j = threadIdx.x;  // 256
  float s = 0.f, s2 = 0.f;
  for (int r = blockIdx.x; r < NN; r += gridDim.x){
    float v = H[(size_t)r * 256 + j];
    if (j < 128) v = fmaxf(v, 0.f);
    s += v; s2 += v * v;
  }
  atomicAdd(&stats[j], s);
  atomicAdd(&stats[256 + j], s2);
}

__global__ void k_bncoef(const float* __restrict__ stats, const float* __restrict__ bnp,
                         float* __restrict__ coef){
  int j = threadIdx.x;  // 256
  const float invN = 1.f / (float)NN;
  float mu = stats[j] * invN;
  float var = stats[256 + j] * invN - mu * mu;
  int jj = (j < 128) ? j : j - 128;
  float g = bnp[(j < 128 ? 0 : 2) * 128 + jj];
  float b = bnp[(j < 128 ? 1 : 3) * 128 + jj];
  float sc = g * rsqrtf(var + 1e-3f);
  coef[j] = sc;
  coef[256 + j] = b - mu * sc;
}

__global__ void k_bnapply(const float* __restrict__ H, const float* __restrict__ coef,
                          unsigned short* __restrict__ OUT){
  int j = threadIdx.x;  // 256
  float sc = coef[j], sh = coef[256 + j];
  for (int r = blockIdx.x; r < NN; r += gridDim.x){
    float v = H[(size_t)r * 256 + j];
    if (j < 128) v = fmaxf(v, 0.f);
    OUT[(size_t)r * 256 + j] = f2h(v * sc + sh);
  }
}

// ---------------- z = h1 @ We + be  (256 -> 16) ----------------
__global__ void k_zdense(const unsigned short* __restrict__ H, const float* __restrict__ We,
                         const float* __restrict__ be, float* __restrict__ Z){
  __shared__ float Hs[16 * 256];
  __shared__ float Ws[256 * 16];
  int t = threadIdx.x;
  int r0 = blockIdx.x * 16;
  for (int i = t; i < 4096; i += 256){
    Hs[i] = h2f(H[(size_t)r0 * 256 + i]);
    Ws[i] = We[i];
  }
  __syncthreads();
  int r = t >> 4, m = t & 15;
  float accv = be[m];
  const float* hrow = Hs + r * 256;
  #pragma unroll 8
  for (int k = 0; k < 256; k++) accv += hrow[k] * Ws[k * 16 + m];
  Z[(size_t)(r0 + r) * 16 + m] = accv;
}

// ---------------- per-edge softmax over 16 machines ----------------
__global__ void k_edge(const int* __restrict__ rows, const int* __restrict__ cols,
                       const float* __restrict__ vals, const float* __restrict__ Z,
                       float* __restrict__ out){
  int e = blockIdx.x * blockDim.x + threadIdx.x;
  if (e >= NE) return;
  int r = rows[e], c = cols[e];
  float v = vals[e];
  const float4* zr = (const float4*)(Z + (size_t)r * 16);
  const float4* zc = (const float4*)(Z + (size_t)c * 16);
  float s[16];
  #pragma unroll
  for (int q = 0; q < 4; q++){
    float4 a = zr[q], b = zc[q];
    s[q * 4 + 0] = v * (a.x + b.x);
    s[q * 4 + 1] = v * (a.y + b.y);
    s[q * 4 + 2] = v * (a.z + b.z);
    s[q * 4 + 3] = v * (a.w + b.w);
  }
  float mx = s[0];
  #pragma unroll
  for (int i = 1; i < 16; i++) mx = fmaxf(mx, s[i]);
  float sum = 0.f;
  #pragma unroll
  for (int i = 0; i < 16; i++){ s[i] = __expf(s[i] - mx); sum += s[i]; }
  float inv = 1.f / sum;
  float4* po = (float4*)(out + (size_t)e * 16);
  #pragma unroll
  for (int q = 0; q < 4; q++)
    po[q] = make_float4(s[q*4+0]*inv, s[q*4+1]*inv, s[q*4+2]*inv, s[q*4+3]*inv);
}

extern "C" void kernel_launch(void* const* d_in, const int* in_sizes, int n_in,
                              void* d_out, int out_size, void* d_ws, size_t ws_size,
                              hipStream_t stream){
  const float* x    = (const float*)d_in[0];
  const int* rows   = (const int*)d_in[1];
  const int* cols   = (const int*)d_in[2];
  const float* vals = (const float*)d_in[3];
  const float* l0Wa = (const float*)d_in[4];
  const float* l0Wb = (const float*)d_in[5];
  const float* l0bn = (const float*)d_in[6];
  const float* l1Wa = (const float*)d_in[7];
  const float* l1Wb = (const float*)d_in[8];
  const float* l1bn = (const float*)d_in[9];
  const float* We   = (const float*)d_in[10];
  const float* be   = (const float*)d_in[11];
  float* out        = (float*)d_out;

  uint8_t* p = (uint8_t*)d_ws;
  auto take = [&](size_t b) -> void* { void* q = (void*)p; p += (b + 255) & ~(size_t)255; return q; };
  int*   rowptr = (int*)take((size_t)(NN + 1) * 4);
  int*   cnt    = (int*)take((size_t)NN * 4);
  int*   fill   = (int*)take((size_t)NN * 4);
  int*   colss  = (int*)take((size_t)NE * 4);
  float* valss  = (float*)take((size_t)NE * 4);
  unsigned short* WT0 = (unsigned short*)take((size_t)256 * 512 * 2);
  unsigned short* WT1 = (unsigned short*)take((size_t)256 * 1024 * 2);
  float* stats  = (float*)take(512 * 4);
  float* coef   = (float*)take(512 * 4);
  float* Z      = (float*)take((size_t)NN * 16 * 4);
  float* Hpre   = (float*)take((size_t)NN * 256 * 4);
  unsigned short* x16 = (unsigned short*)take((size_t)NN * 128 * 2);
  unsigned short* buf[5];
  for (int i = 0; i < 5; i++) buf[i] = (unsigned short*)take((size_t)NN * 256 * 2);

  // CSR build (workspace is poisoned every call — rebuild everything)
  hipMemsetAsync(cnt, 0, (size_t)NN * 4, stream);
  hipMemsetAsync(fill, 0, (size_t)NN * 4, stream);
  k_hist<<<NE / 256, 256, 0, stream>>>(rows, cnt);
  k_scan<<<1, 1024, 0, stream>>>(cnt, rowptr);
  k_scatter<<<NE / 256, 256, 0, stream>>>(rows, cols, vals, rowptr, fill, colss, valss);
  k_buildWT<<<(256 * 512) / 256, 256, 0, stream>>>(l0Wa, l0Wb, WT0, 128);
  k_buildWT<<<(256 * 1024) / 256, 256, 0, stream>>>(l1Wa, l1Wb, WT1, 256);
  k_cast<<<(NN * 128 / 4 + 255) / 256, 256, 0, stream>>>(x, x16, NN * 128 / 4);

  dim3 gg(NP / 128, 2);

  // ---- layer 0 ----
  k_spmm<128><<<NN / 4, 256, 0, stream>>>(rowptr, colss, valss, x16,    buf[0]); // a0
  k_spmm<128><<<NN / 4, 256, 0, stream>>>(rowptr, colss, valss, buf[0], buf[1]); // a1
  k_spmm<128><<<NN / 4, 256, 0, stream>>>(rowptr, colss, valss, buf[1], buf[2]); // tmp = A a1
  k_spmm<128><<<NN / 4, 256, 0, stream>>>(rowptr, colss, valss, buf[2], buf[3]); // a2 = A tmp
  k_gemm4<128><<<gg, 256, 0, stream>>>(x16, buf[0], buf[1], buf[3], WT0, Hpre);
  hipMemsetAsync(stats, 0, 512 * 4, stream);
  k_bnstats<<<512, 256, 0, stream>>>(Hpre, stats);
  k_bncoef<<<1, 256, 0, stream>>>(stats, l0bn, coef);
  k_bnapply<<<2048, 256, 0, stream>>>(Hpre, coef, buf[4]);                        // h0

  // ---- layer 1 ----
  k_spmm<256><<<NN / 4, 256, 0, stream>>>(rowptr, colss, valss, buf[4], buf[0]); // a0'
  k_spmm<256><<<NN / 4, 256, 0, stream>>>(rowptr, colss, valss, buf[0], buf[1]); // a1'
  k_spmm<256><<<NN / 4, 256, 0, stream>>>(rowptr, colss, valss, buf[1], buf[2]); // tmp'
  k_spmm<256><<<NN / 4, 256, 0, stream>>>(rowptr, colss, valss, buf[2], buf[3]); // a2'
  k_gemm4<256><<<gg, 256, 0, stream>>>(buf[4], buf[0], buf[1], buf[3], WT1, Hpre);
  hipMemsetAsync(stats, 0, 512 * 4, stream);
  k_bnstats<<<512, 256, 0, stream>>>(Hpre, stats);
  k_bncoef<<<1, 256, 0, stream>>>(stats, l1bn, coef);
  k_bnapply<<<2048, 256, 0, stream>>>(Hpre, coef, buf[2]);                        // h1 (tmp' dead)

  k_zdense<<<NN / 16, 256, 0, stream>>>(buf[2], We, be, Z);
  k_edge<<<NE / 256, 256, 0, stream>>>(rows, cols, vals, Z, out);
}

// Round 4
// 777.196 us; speedup vs baseline: 1.5824x; 1.5824x over previous
//
#include <hip/hip_runtime.h>
#include <stdint.h>

#define NN 50000
#define NE 800000
#define NP 50048   // 391*128, padded row count for 128-row gemm tiles
#define SCANB 196  // ceil(NN/256)

typedef _Float16 f16x8 __attribute__((ext_vector_type(8)));
typedef float f32x4 __attribute__((ext_vector_type(4)));

__device__ __forceinline__ float h2f(unsigned short u){
  union { unsigned short u; _Float16 h; } x; x.u = u; return (float)x.h;
}
__device__ __forceinline__ unsigned short f2h(float f){
  union { _Float16 h; unsigned short u; } x; x.h = (_Float16)f; return x.u;  // v_cvt_f16_f32, RNE
}
__device__ __forceinline__ void load_lds16(const void* g, void* l){
  __builtin_amdgcn_global_load_lds((const __attribute__((address_space(1))) void*)g,
                                   (__attribute__((address_space(3))) void*)l, 16, 0, 0);
}

// ---------------- fp32 -> fp16 cast (vectorized) ----------------
__global__ void k_cast(const float* __restrict__ src, unsigned short* __restrict__ dst, int n4){
  int i = blockIdx.x*blockDim.x + threadIdx.x;
  if (i >= n4) return;
  float4 v = ((const float4*)src)[i];
  uint2 o;
  o.x = (unsigned int)f2h(v.x) | ((unsigned int)f2h(v.y) << 16);
  o.y = (unsigned int)f2h(v.z) | ((unsigned int)f2h(v.w) << 16);
  ((uint2*)dst)[i] = o;
}

// ---------------- CSR build ----------------
__global__ void k_hist(const int* __restrict__ rows, int* __restrict__ cnt){
  int e = blockIdx.x*blockDim.x + threadIdx.x;
  if (e < NE) atomicAdd(&cnt[rows[e]], 1);
}

// parallel scan, pass 1: per-block inclusive scan of 256 counts -> exclusive prefix + block sum
__global__ void k_scan1(const int* __restrict__ cnt, int* __restrict__ rowptr, int* __restrict__ bsum){
  __shared__ int sh[256];
  int t = threadIdx.x, b = blockIdx.x;
  int idx = b * 256 + t;
  int v = (idx < NN) ? cnt[idx] : 0;
  sh[t] = v; __syncthreads();
  #pragma unroll
  for (int off = 1; off < 256; off <<= 1){
    int u = (t >= off) ? sh[t - off] : 0;
    __syncthreads();
    sh[t] += u;
    __syncthreads();
  }
  if (idx < NN) rowptr[idx] = sh[t] - v;   // exclusive within block
  if (t == 255) bsum[b] = sh[255];
}

// pass 2: exclusive scan of the 196 block sums (+ grand total at [SCANB])
__global__ void k_scan2(const int* __restrict__ bsum, int* __restrict__ boff){
  __shared__ int sh[256];
  int t = threadIdx.x;
  int v = (t < SCANB) ? bsum[t] : 0;
  sh[t] = v; __syncthreads();
  #pragma unroll
  for (int off = 1; off < 256; off <<= 1){
    int u = (t >= off) ? sh[t - off] : 0;
    __syncthreads();
    sh[t] += u;
    __syncthreads();
  }
  if (t < SCANB) boff[t] = sh[t] - v;
  if (t == SCANB) boff[SCANB] = sh[255];   // total (== NE)
}

// pass 3: add block offsets; rowptr[NN] = total
__global__ void k_scan3(int* __restrict__ rowptr, const int* __restrict__ boff){
  int idx = blockIdx.x * 256 + threadIdx.x;
  if (idx < NN) rowptr[idx] += boff[idx >> 8];
  else if (idx == NN) rowptr[NN] = boff[SCANB];
}

__global__ void k_scatter(const int* __restrict__ rows, const int* __restrict__ cols,
                          const float* __restrict__ vals,
                          const int* __restrict__ rowptr, int* __restrict__ fill,
                          int* __restrict__ colss, float* __restrict__ valss){
  int e = blockIdx.x*blockDim.x + threadIdx.x;
  if (e >= NE) return;
  int r = rows[e];
  int p = rowptr[r] + atomicAdd(&fill[r], 1);
  colss[p] = cols[e];
  valss[p] = vals[e];
}

// ---------------- weight concat: WT[j][k], j=out col (alpha 0-127 | beta 128-255), k in 4*Fin ----------------
__global__ void k_buildWT(const float* __restrict__ Wa, const float* __restrict__ Wb,
                          unsigned short* __restrict__ WT, int Fin){
  int Ktot = 4 * Fin;
  int idx = blockIdx.x*blockDim.x + threadIdx.x;
  if (idx >= 256 * Ktot) return;
  int j = idx / Ktot, k = idx - j * Ktot;
  int seg = k / Fin, ki = k - seg * Fin;
  const float* W = (j < 128) ? Wa : Wb;
  int jj = (j < 128) ? j : j - 128;
  int stride = Fin * 128;
  float v;
  if (seg == 0)
    v = W[0*stride + ki*128 + jj] + W[1*stride + ki*128 + jj] + W[2*stride + ki*128 + jj];
  else
    v = W[(seg + 2)*stride + ki*128 + jj];
  WT[j*Ktot + k] = f2h(v);
}

// ---------------- SpMM: one wave per row; cooperative edge preload + shfl broadcast,
// gathers issued in unrolled batches of 8 (independent loads in flight). fp32 accumulate.
template<int F>
__global__ void k_spmm(const int* __restrict__ rowptr, const int* __restrict__ colss,
                       const float* __restrict__ valss,
                       const unsigned short* __restrict__ X, unsigned short* __restrict__ Y){
  int row = blockIdx.x * (blockDim.x >> 6) + (threadIdx.x >> 6);
  if (row >= NN) return;
  int lane = threadIdx.x & 63;
  constexpr int P = F / 64;        // 2 (F=128) or 4 (F=256) elems per lane
  float acc[P];
  #pragma unroll
  for (int i = 0; i < P; i++) acc[i] = 0.f;
  int s = rowptr[row], e = rowptr[row + 1];
  for (int base = s; base < e; base += 64){
    int idx = base + lane;
    bool ok = idx < e;
    int   cc = ok ? colss[idx] : 0;     // OOB edges: col 0, val 0 -> contributes exactly 0
    float vv = ok ? valss[idx] : 0.f;
    int n = e - base; if (n > 64) n = 64;
    for (int jb = 0; jb < n; jb += 8){
      int cj[8]; float vj[8];
      #pragma unroll
      for (int u = 0; u < 8; u++){
        cj[u] = __shfl(cc, jb + u);
        vj[u] = __shfl(vv, jb + u);
      }
      if (P == 2){
        unsigned int g[8];
        #pragma unroll
        for (int u = 0; u < 8; u++)
          g[u] = *(const unsigned int*)(X + (size_t)cj[u] * F + lane * P);
        #pragma unroll
        for (int u = 0; u < 8; u++){
          acc[0] += vj[u] * h2f((unsigned short)g[u]);
          acc[1] += vj[u] * h2f((unsigned short)(g[u] >> 16));
        }
      } else {
        uint2 g[8];
        #pragma unroll
        for (int u = 0; u < 8; u++)
          g[u] = *(const uint2*)(X + (size_t)cj[u] * F + lane * P);
        #pragma unroll
        for (int u = 0; u < 8; u++){
          acc[0] += vj[u] * h2f((unsigned short)g[u].x);
          acc[1] += vj[u] * h2f((unsigned short)(g[u].x >> 16));
          acc[2] += vj[u] * h2f((unsigned short)g[u].y);
          acc[3] += vj[u] * h2f((unsigned short)(g[u].y >> 16));
        }
      }
    }
  }
  unsigned short* dst = Y + (size_t)row * F + lane * P;
  if (P == 2){
    unsigned int o = (unsigned int)f2h(acc[0]) | ((unsigned int)f2h(acc[1]) << 16);
    *(unsigned int*)dst = o;
  } else {
    uint2 o;
    o.x = (unsigned int)f2h(acc[0]) | ((unsigned int)f2h(acc[1]) << 16);
    o.y = (unsigned int)f2h(acc[2]) | ((unsigned int)f2h(acc[3]) << 16);
    *(uint2*)dst = o;
  }
}

// ---------------- 4-source fused GEMM: C(N x 256) = [A0|A1|A2|A3](N x 4*FIN) @ WT^T ----------------
template<int FIN>
__global__ __launch_bounds__(256) void k_gemm4(
    const unsigned short* __restrict__ A0, const unsigned short* __restrict__ A1,
    const unsigned short* __restrict__ A2, const unsigned short* __restrict__ A3,
    const unsigned short* __restrict__ BT, float* __restrict__ C){
  constexpr int KTOT = 4 * FIN;
  __shared__ unsigned short As[128 * 32];
  __shared__ unsigned short Bs[128 * 32];
  int tid = threadIdx.x, lane = tid & 63;
  int wm = (tid >> 6) & 1, wn = tid >> 7;
  int bm = blockIdx.x, bn = blockIdx.y;

  f32x4 acc[4][4];
  #pragma unroll
  for (int i = 0; i < 4; i++)
    #pragma unroll
    for (int j = 0; j < 4; j++) acc[i][j] = (f32x4){0.f, 0.f, 0.f, 0.f};

  int ac = (tid & 3) * 8;
  int gr0 = bm * 128 + (tid >> 2);        if (gr0 >= NN) gr0 = NN - 1;
  int gr1 = bm * 128 + ((256 + tid) >> 2); if (gr1 >= NN) gr1 = NN - 1;
  int br0 = (tid >> 2), br1 = ((256 + tid) >> 2);
  const unsigned short* Bb = BT + (size_t)(bn * 128) * KTOT;
  unsigned short* Adst0 = As + (size_t)(tid & ~63) * 8;
  unsigned short* Adst1 = As + (size_t)(256 + (tid & ~63)) * 8;
  unsigned short* Bdst0 = Bs + (size_t)(tid & ~63) * 8;
  unsigned short* Bdst1 = Bs + (size_t)(256 + (tid & ~63)) * 8;

  int m0 = wm * 64 + (lane & 15);
  int n0 = wn * 64 + (lane & 15);
  int qk = (lane >> 4) * 8;

  #pragma unroll
  for (int seg = 0; seg < 4; seg++){
    const unsigned short* Asrc = (seg == 0) ? A0 : (seg == 1) ? A1 : (seg == 2) ? A2 : A3;
    const unsigned short* Bseg = Bb + seg * FIN;
    for (int kl = 0; kl < FIN; kl += 32){
      load_lds16(Asrc + (size_t)gr0 * FIN + kl + ac, Adst0);
      load_lds16(Asrc + (size_t)gr1 * FIN + kl + ac, Adst1);
      load_lds16(Bseg + (size_t)br0 * KTOT + kl + ac, Bdst0);
      load_lds16(Bseg + (size_t)br1 * KTOT + kl + ac, Bdst1);
      __syncthreads();
      f16x8 af[4], bfr[4];
      #pragma unroll
      for (int i = 0; i < 4; i++) af[i]  = *(const f16x8*)(As + (m0 + i * 16) * 32 + qk);
      #pragma unroll
      for (int j = 0; j < 4; j++) bfr[j] = *(const f16x8*)(Bs + (n0 + j * 16) * 32 + qk);
      #pragma unroll
      for (int i = 0; i < 4; i++)
        #pragma unroll
        for (int j = 0; j < 4; j++)
          acc[i][j] = __builtin_amdgcn_mfma_f32_16x16x32_f16(af[i], bfr[j], acc[i][j], 0, 0, 0);
      __syncthreads();
    }
  }
  int cn = bn * 128 + wn * 64 + (lane & 15);
  int rb = bm * 128 + wm * 64 + ((lane >> 4) << 2);
  #pragma unroll
  for (int i = 0; i < 4; i++)
    #pragma unroll
    for (int j = 0; j < 4; j++)
      #pragma unroll
      for (int g = 0; g < 4; g++){
        int rr = rb + i * 16 + g;
        if (rr < NN) C[(size_t)rr * 256 + cn + j * 16] = acc[i][j][g];
      }
}

// ---------------- BatchNorm (training-mode stats), relu-before-stats on alpha half ----------------
__global__ void k_bnstats(const float* __restrict__ H, float* __restrict__ stats){
  int j = threadIdx.x;  // 256
  float s = 0.f, s2 = 0.f;
  for (int r = blockIdx.x; r < NN; r += gridDim.x){
    float v = H[(size_t)r * 256 + j];
    if (j < 128) v = fmaxf(v, 0.f);
    s += v; s2 += v * v;
  }
  atomicAdd(&stats[j], s);
  atomicAdd(&stats[256 + j], s2);
}

__global__ void k_bncoef(const float* __restrict__ stats, const float* __restrict__ bnp,
                         float* __restrict__ coef){
  int j = threadIdx.x;  // 256
  const float invN = 1.f / (float)NN;
  float mu = stats[j] * invN;
  float var = stats[256 + j] * invN - mu * mu;
  int jj = (j < 128) ? j : j - 128;
  float g = bnp[(j < 128 ? 0 : 2) * 128 + jj];
  float b = bnp[(j < 128 ? 1 : 3) * 128 + jj];
  float sc = g * rsqrtf(var + 1e-3f);
  coef[j] = sc;
  coef[256 + j] = b - mu * sc;
}

__global__ void k_bnapply(const float* __restrict__ H, const float* __restrict__ coef,
                          unsigned short* __restrict__ OUT){
  int j = threadIdx.x;  // 256
  float sc = coef[j], sh = coef[256 + j];
  for (int r = blockIdx.x; r < NN; r += gridDim.x){
    float v = H[(size_t)r * 256 + j];
    if (j < 128) v = fmaxf(v, 0.f);
    OUT[(size_t)r * 256 + j] = f2h(v * sc + sh);
  }
}

// ---------------- fused layer-1 BN-apply + z = h1 @ We + be (h1 never materialized) ----------------
__global__ void k_bnzdense(const float* __restrict__ H, const float* __restrict__ coef,
                           const float* __restrict__ We, const float* __restrict__ be,
                           float* __restrict__ Z){
  __shared__ float Hs[16 * 256];
  __shared__ float Ws[256 * 16];
  int t = threadIdx.x;
  int r0 = blockIdx.x * 16;
  for (int i = t; i < 4096; i += 256){
    int col = i & 255;
    float v = H[(size_t)r0 * 256 + i];
    if (col < 128) v = fmaxf(v, 0.f);
    Hs[i] = v * coef[col] + coef[256 + col];
    Ws[i] = We[i];
  }
  __syncthreads();
  int r = t >> 4, m = t & 15;
  float accv = be[m];
  const float* hrow = Hs + r * 256;
  #pragma unroll 8
  for (int k = 0; k < 256; k++) accv += hrow[k] * Ws[k * 16 + m];
  Z[(size_t)(r0 + r) * 16 + m] = accv;
}

// ---------------- per-edge softmax over 16 machines ----------------
__global__ void k_edge(const int* __restrict__ rows, const int* __restrict__ cols,
                       const float* __restrict__ vals, const float* __restrict__ Z,
                       float* __restrict__ out){
  int e = blockIdx.x * blockDim.x + threadIdx.x;
  if (e >= NE) return;
  int r = rows[e], c = cols[e];
  float v = vals[e];
  const float4* zr = (const float4*)(Z + (size_t)r * 16);
  const float4* zc = (const float4*)(Z + (size_t)c * 16);
  float s[16];
  #pragma unroll
  for (int q = 0; q < 4; q++){
    float4 a = zr[q], b = zc[q];
    s[q * 4 + 0] = v * (a.x + b.x);
    s[q * 4 + 1] = v * (a.y + b.y);
    s[q * 4 + 2] = v * (a.z + b.z);
    s[q * 4 + 3] = v * (a.w + b.w);
  }
  float mx = s[0];
  #pragma unroll
  for (int i = 1; i < 16; i++) mx = fmaxf(mx, s[i]);
  float sum = 0.f;
  #pragma unroll
  for (int i = 0; i < 16; i++){ s[i] = __expf(s[i] - mx); sum += s[i]; }
  float inv = 1.f / sum;
  float4* po = (float4*)(out + (size_t)e * 16);
  #pragma unroll
  for (int q = 0; q < 4; q++)
    po[q] = make_float4(s[q*4+0]*inv, s[q*4+1]*inv, s[q*4+2]*inv, s[q*4+3]*inv);
}

extern "C" void kernel_launch(void* const* d_in, const int* in_sizes, int n_in,
                              void* d_out, int out_size, void* d_ws, size_t ws_size,
                              hipStream_t stream){
  const float* x    = (const float*)d_in[0];
  const int* rows   = (const int*)d_in[1];
  const int* cols   = (const int*)d_in[2];
  const float* vals = (const float*)d_in[3];
  const float* l0Wa = (const float*)d_in[4];
  const float* l0Wb = (const float*)d_in[5];
  const float* l0bn = (const float*)d_in[6];
  const float* l1Wa = (const float*)d_in[7];
  const float* l1Wb = (const float*)d_in[8];
  const float* l1bn = (const float*)d_in[9];
  const float* We   = (const float*)d_in[10];
  const float* be   = (const float*)d_in[11];
  float* out        = (float*)d_out;

  uint8_t* p = (uint8_t*)d_ws;
  auto take = [&](size_t b) -> void* { void* q = (void*)p; p += (b + 255) & ~(size_t)255; return q; };
  int*   rowptr = (int*)take((size_t)(NN + 1) * 4);
  int*   cnt    = (int*)take((size_t)NN * 4);
  int*   fill   = (int*)take((size_t)NN * 4);
  int*   bsum   = (int*)take((size_t)SCANB * 4);
  int*   boff   = (int*)take((size_t)(SCANB + 1) * 4);
  int*   colss  = (int*)take((size_t)NE * 4);
  float* valss  = (float*)take((size_t)NE * 4);
  unsigned short* WT0 = (unsigned short*)take((size_t)256 * 512 * 2);
  unsigned short* WT1 = (unsigned short*)take((size_t)256 * 1024 * 2);
  float* stats  = (float*)take(512 * 4);
  float* coef   = (float*)take(512 * 4);
  float* Z      = (float*)take((size_t)NN * 16 * 4);
  float* Hpre   = (float*)take((size_t)NN * 256 * 4);
  unsigned short* x16 = (unsigned short*)take((size_t)NN * 128 * 2);
  unsigned short* buf[5];
  for (int i = 0; i < 5; i++) buf[i] = (unsigned short*)take((size_t)NN * 256 * 2);

  // CSR build (workspace is poisoned every call — rebuild everything)
  hipMemsetAsync(cnt, 0, (size_t)NN * 4, stream);
  hipMemsetAsync(fill, 0, (size_t)NN * 4, stream);
  k_hist<<<NE / 256, 256, 0, stream>>>(rows, cnt);
  k_scan1<<<SCANB, 256, 0, stream>>>(cnt, rowptr, bsum);
  k_scan2<<<1, 256, 0, stream>>>(bsum, boff);
  k_scan3<<<SCANB, 256, 0, stream>>>(rowptr, boff);
  k_scatter<<<NE / 256, 256, 0, stream>>>(rows, cols, vals, rowptr, fill, colss, valss);
  k_buildWT<<<(256 * 512) / 256, 256, 0, stream>>>(l0Wa, l0Wb, WT0, 128);
  k_buildWT<<<(256 * 1024) / 256, 256, 0, stream>>>(l1Wa, l1Wb, WT1, 256);
  k_cast<<<(NN * 128 / 4 + 255) / 256, 256, 0, stream>>>(x, x16, NN * 128 / 4);

  dim3 gg(NP / 128, 2);

  // ---- layer 0 ----
  k_spmm<128><<<NN / 4, 256, 0, stream>>>(rowptr, colss, valss, x16,    buf[0]); // a0
  k_spmm<128><<<NN / 4, 256, 0, stream>>>(rowptr, colss, valss, buf[0], buf[1]); // a1
  k_spmm<128><<<NN / 4, 256, 0, stream>>>(rowptr, colss, valss, buf[1], buf[2]); // tmp = A a1
  k_spmm<128><<<NN / 4, 256, 0, stream>>>(rowptr, colss, valss, buf[2], buf[3]); // a2 = A tmp
  k_gemm4<128><<<gg, 256, 0, stream>>>(x16, buf[0], buf[1], buf[3], WT0, Hpre);
  hipMemsetAsync(stats, 0, 512 * 4, stream);
  k_bnstats<<<512, 256, 0, stream>>>(Hpre, stats);
  k_bncoef<<<1, 256, 0, stream>>>(stats, l0bn, coef);
  k_bnapply<<<2048, 256, 0, stream>>>(Hpre, coef, buf[4]);                        // h0

  // ---- layer 1 ----
  k_spmm<256><<<NN / 4, 256, 0, stream>>>(rowptr, colss, valss, buf[4], buf[0]); // a0'
  k_spmm<256><<<NN / 4, 256, 0, stream>>>(rowptr, colss, valss, buf[0], buf[1]); // a1'
  k_spmm<256><<<NN / 4, 256, 0, stream>>>(rowptr, colss, valss, buf[1], buf[2]); // tmp'
  k_spmm<256><<<NN / 4, 256, 0, stream>>>(rowptr, colss, valss, buf[2], buf[3]); // a2'
  k_gemm4<256><<<gg, 256, 0, stream>>>(buf[4], buf[0], buf[1], buf[3], WT1, Hpre);
  hipMemsetAsync(stats, 0, 512 * 4, stream);
  k_bnstats<<<512, 256, 0, stream>>>(Hpre, stats);
  k_bncoef<<<1, 256, 0, stream>>>(stats, l1bn, coef);
  k_bnzdense<<<NN / 16, 256, 0, stream>>>(Hpre, coef, We, be, Z);               // fused BN+zdense

  k_edge<<<NE / 256, 256, 0, stream>>>(rows, cols, vals, Z, out);
}

// Round 5
// 758.411 us; speedup vs baseline: 1.6216x; 1.0248x over previous
//
#include <hip/hip_runtime.h>
#include <stdint.h>

#define NN 50000
#define NE 800000
#define NP 50048   // 391*128, padded row count for 128-row gemm tiles
#define SCANB 196  // ceil(NN/256)

typedef _Float16 f16x8 __attribute__((ext_vector_type(8)));
typedef float f32x4 __attribute__((ext_vector_type(4)));

__device__ __forceinline__ float h2f(unsigned short u){
  union { unsigned short u; _Float16 h; } x; x.u = u; return (float)x.h;
}
__device__ __forceinline__ unsigned short f2h(float f){
  union { _Float16 h; unsigned short u; } x; x.h = (_Float16)f; return x.u;  // v_cvt_f16_f32, RNE
}
__device__ __forceinline__ void load_lds16(const void* g, void* l){
  __builtin_amdgcn_global_load_lds((const __attribute__((address_space(1))) void*)g,
                                   (__attribute__((address_space(3))) void*)l, 16, 0, 0);
}

// ---------------- fp32 -> fp16 cast (vectorized) ----------------
__global__ void k_cast(const float* __restrict__ src, unsigned short* __restrict__ dst, int n4){
  int i = blockIdx.x*blockDim.x + threadIdx.x;
  if (i >= n4) return;
  float4 v = ((const float4*)src)[i];
  uint2 o;
  o.x = (unsigned int)f2h(v.x) | ((unsigned int)f2h(v.y) << 16);
  o.y = (unsigned int)f2h(v.z) | ((unsigned int)f2h(v.w) << 16);
  ((uint2*)dst)[i] = o;
}

// ---------------- CSR build ----------------
__global__ void k_hist(const int* __restrict__ rows, int* __restrict__ cnt){
  int e = blockIdx.x*blockDim.x + threadIdx.x;
  if (e < NE) atomicAdd(&cnt[rows[e]], 1);
}

// pass 1: per-block exclusive scan of 256 counts + block sum
__global__ void k_scan1(const int* __restrict__ cnt, int* __restrict__ rowptr, int* __restrict__ bsum){
  __shared__ int sh[256];
  int t = threadIdx.x, b = blockIdx.x;
  int idx = b * 256 + t;
  int v = (idx < NN) ? cnt[idx] : 0;
  sh[t] = v; __syncthreads();
  #pragma unroll
  for (int off = 1; off < 256; off <<= 1){
    int u = (t >= off) ? sh[t - off] : 0;
    __syncthreads();
    sh[t] += u;
    __syncthreads();
  }
  if (idx < NN) rowptr[idx] = sh[t] - v;   // exclusive within block
  if (t == 255) bsum[b] = sh[255];
}

// pass 2 (merged): every block scans the 196 block sums in LDS, adds its own offset
__global__ void k_scan3(int* __restrict__ rowptr, const int* __restrict__ bsum){
  __shared__ int sh[256];
  int t = threadIdx.x, b = blockIdx.x;
  int v = (t < SCANB) ? bsum[t] : 0;
  sh[t] = v; __syncthreads();
  #pragma unroll
  for (int off = 1; off < 256; off <<= 1){
    int u = (t >= off) ? sh[t - off] : 0;
    __syncthreads();
    sh[t] += u;
    __syncthreads();
  }
  int boffb = (b == 0) ? 0 : sh[b - 1];
  int total = sh[SCANB - 1];
  int idx = b * 256 + t;
  if (idx < NN) rowptr[idx] += boffb;
  else if (idx == NN) rowptr[NN] = total;
}

__global__ void k_scatter(const int* __restrict__ rows, const int* __restrict__ cols,
                          const float* __restrict__ vals,
                          const int* __restrict__ rowptr, int* __restrict__ fill,
                          int* __restrict__ colss, float* __restrict__ valss){
  int e = blockIdx.x*blockDim.x + threadIdx.x;
  if (e >= NE) return;
  int r = rows[e];
  int p = rowptr[r] + atomicAdd(&fill[r], 1);
  colss[p] = cols[e];
  valss[p] = vals[e];
}

// ---------------- weight concat: WT[j][k], j=out col (alpha 0-127 | beta 128-255), k in 4*Fin ----------------
__global__ void k_buildWT(const float* __restrict__ Wa, const float* __restrict__ Wb,
                          unsigned short* __restrict__ WT, int Fin){
  int Ktot = 4 * Fin;
  int idx = blockIdx.x*blockDim.x + threadIdx.x;
  if (idx >= 256 * Ktot) return;
  int j = idx / Ktot, k = idx - j * Ktot;
  int seg = k / Fin, ki = k - seg * Fin;
  const float* W = (j < 128) ? Wa : Wb;
  int jj = (j < 128) ? j : j - 128;
  int stride = Fin * 128;
  float v;
  if (seg == 0)
    v = W[0*stride + ki*128 + jj] + W[1*stride + ki*128 + jj] + W[2*stride + ki*128 + jj];
  else
    v = W[(seg + 2)*stride + ki*128 + jj];
  WT[j*Ktot + k] = f2h(v);
}

// ---------------- SpMM: one wave per row; shfl broadcast, 16 gathers in flight ----------------
template<int F>
__global__ void k_spmm(const int* __restrict__ rowptr, const int* __restrict__ colss,
                       const float* __restrict__ valss,
                       const unsigned short* __restrict__ X, unsigned short* __restrict__ Y){
  int row = blockIdx.x * (blockDim.x >> 6) + (threadIdx.x >> 6);
  if (row >= NN) return;
  int lane = threadIdx.x & 63;
  constexpr int P = F / 64;        // 2 (F=128) or 4 (F=256) elems per lane
  float acc[P];
  #pragma unroll
  for (int i = 0; i < P; i++) acc[i] = 0.f;
  int s = rowptr[row], e = rowptr[row + 1];
  for (int base = s; base < e; base += 64){
    int idx = base + lane;
    bool ok = idx < e;
    int   cc = ok ? colss[idx] : 0;     // OOB edges: col 0, val 0 -> contributes exactly 0
    float vv = ok ? valss[idx] : 0.f;
    int n = e - base; if (n > 64) n = 64;
    int nr = (n + 15) & ~15;            // pad to 16: padded edges have v=0 -> exact no-op
    for (int jb = 0; jb < nr; jb += 16){
      int cj[16]; float vj[16];
      #pragma unroll
      for (int u = 0; u < 16; u++){
        cj[u] = __shfl(cc, jb + u);
        vj[u] = __shfl(vv, jb + u);
      }
      if (P == 2){
        unsigned int g[16];
        #pragma unroll
        for (int u = 0; u < 16; u++)
          g[u] = *(const unsigned int*)(X + (size_t)cj[u] * F + lane * P);
        #pragma unroll
        for (int u = 0; u < 16; u++){
          acc[0] += vj[u] * h2f((unsigned short)g[u]);
          acc[1] += vj[u] * h2f((unsigned short)(g[u] >> 16));
        }
      } else {
        uint2 g[16];
        #pragma unroll
        for (int u = 0; u < 16; u++)
          g[u] = *(const uint2*)(X + (size_t)cj[u] * F + lane * P);
        #pragma unroll
        for (int u = 0; u < 16; u++){
          acc[0] += vj[u] * h2f((unsigned short)g[u].x);
          acc[1] += vj[u] * h2f((unsigned short)(g[u].x >> 16));
          acc[2] += vj[u] * h2f((unsigned short)g[u].y);
          acc[3] += vj[u] * h2f((unsigned short)(g[u].y >> 16));
        }
      }
    }
  }
  unsigned short* dst = Y + (size_t)row * F + lane * P;
  if (P == 2){
    unsigned int o = (unsigned int)f2h(acc[0]) | ((unsigned int)f2h(acc[1]) << 16);
    *(unsigned int*)dst = o;
  } else {
    uint2 o;
    o.x = (unsigned int)f2h(acc[0]) | ((unsigned int)f2h(acc[1]) << 16);
    o.y = (unsigned int)f2h(acc[2]) | ((unsigned int)f2h(acc[3]) << 16);
    *(uint2*)dst = o;
  }
}

// ---------------- 4-source fused GEMM + BN-stats epilogue; H stored fp16 ----------------
template<int FIN>
__global__ __launch_bounds__(256) void k_gemm4(
    const unsigned short* __restrict__ A0, const unsigned short* __restrict__ A1,
    const unsigned short* __restrict__ A2, const unsigned short* __restrict__ A3,
    const unsigned short* __restrict__ BT, unsigned short* __restrict__ Hp,
    float* __restrict__ stats){
  constexpr int KTOT = 4 * FIN;
  __shared__ unsigned short As[128 * 32];
  __shared__ unsigned short Bs[128 * 32];
  int tid = threadIdx.x, lane = tid & 63;
  int wm = (tid >> 6) & 1, wn = tid >> 7;
  int bm = blockIdx.x, bn = blockIdx.y;

  f32x4 acc[4][4];
  #pragma unroll
  for (int i = 0; i < 4; i++)
    #pragma unroll
    for (int j = 0; j < 4; j++) acc[i][j] = (f32x4){0.f, 0.f, 0.f, 0.f};

  int ac = (tid & 3) * 8;
  int gr0 = bm * 128 + (tid >> 2);        if (gr0 >= NN) gr0 = NN - 1;
  int gr1 = bm * 128 + ((256 + tid) >> 2); if (gr1 >= NN) gr1 = NN - 1;
  int br0 = (tid >> 2), br1 = ((256 + tid) >> 2);
  const unsigned short* Bb = BT + (size_t)(bn * 128) * KTOT;
  unsigned short* Adst0 = As + (size_t)(tid & ~63) * 8;
  unsigned short* Adst1 = As + (size_t)(256 + (tid & ~63)) * 8;
  unsigned short* Bdst0 = Bs + (size_t)(tid & ~63) * 8;
  unsigned short* Bdst1 = Bs + (size_t)(256 + (tid & ~63)) * 8;

  int m0 = wm * 64 + (lane & 15);
  int n0 = wn * 64 + (lane & 15);
  int qk = (lane >> 4) * 8;

  #pragma unroll
  for (int seg = 0; seg < 4; seg++){
    const unsigned short* Asrc = (seg == 0) ? A0 : (seg == 1) ? A1 : (seg == 2) ? A2 : A3;
    const unsigned short* Bseg = Bb + seg * FIN;
    for (int kl = 0; kl < FIN; kl += 32){
      load_lds16(Asrc + (size_t)gr0 * FIN + kl + ac, Adst0);
      load_lds16(Asrc + (size_t)gr1 * FIN + kl + ac, Adst1);
      load_lds16(Bseg + (size_t)br0 * KTOT + kl + ac, Bdst0);
      load_lds16(Bseg + (size_t)br1 * KTOT + kl + ac, Bdst1);
      __syncthreads();
      f16x8 af[4], bfr[4];
      #pragma unroll
      for (int i = 0; i < 4; i++) af[i]  = *(const f16x8*)(As + (m0 + i * 16) * 32 + qk);
      #pragma unroll
      for (int j = 0; j < 4; j++) bfr[j] = *(const f16x8*)(Bs + (n0 + j * 16) * 32 + qk);
      #pragma unroll
      for (int i = 0; i < 4; i++)
        #pragma unroll
        for (int j = 0; j < 4; j++)
          acc[i][j] = __builtin_amdgcn_mfma_f32_16x16x32_f16(af[i], bfr[j], acc[i][j], 0, 0, 0);
      __syncthreads();
    }
  }
  // epilogue: store fp16 H + per-column BN partial stats (relu on alpha half = bn==0)
  int cnb = bn * 128 + wn * 64 + (lane & 15);
  int rb  = bm * 128 + wm * 64 + ((lane >> 4) << 2);
  float sj[4], qj[4];
  #pragma unroll
  for (int j = 0; j < 4; j++){
    float sv = 0.f, qv = 0.f;
    #pragma unroll
    for (int i = 0; i < 4; i++)
      #pragma unroll
      for (int g = 0; g < 4; g++){
        int rr = rb + i * 16 + g;
        float val = acc[i][j][g];
        bool okr = rr < NN;
        if (okr) Hp[(size_t)rr * 256 + cnb + j * 16] = f2h(val);
        float v = okr ? val : 0.f;
        if (bn == 0) v = fmaxf(v, 0.f);
        sv += v; qv += v * v;
      }
    sj[j] = sv; qj[j] = qv;
  }
  #pragma unroll
  for (int j = 0; j < 4; j++){
    sj[j] += __shfl_xor(sj[j], 16); sj[j] += __shfl_xor(sj[j], 32);
    qj[j] += __shfl_xor(qj[j], 16); qj[j] += __shfl_xor(qj[j], 32);
  }
  if (lane < 16){
    #pragma unroll
    for (int j = 0; j < 4; j++){
      int c = bn * 128 + wn * 64 + j * 16 + lane;
      atomicAdd(&stats[c], sj[j]);
      atomicAdd(&stats[256 + c], qj[j]);
    }
  }
}

// ---------------- BN apply (coef computed in-block from stats) ----------------
__global__ void k_bnapply(const unsigned short* __restrict__ Hp, const float* __restrict__ stats,
                          const float* __restrict__ bnp, unsigned short* __restrict__ OUT){
  __shared__ float scs[256], sbs[256];
  int t = threadIdx.x;  // 256
  {
    const float invN = 1.f / (float)NN;
    float mu = stats[t] * invN;
    float var = stats[256 + t] * invN - mu * mu;
    int jj = (t < 128) ? t : t - 128;
    float g = bnp[(t < 128 ? 0 : 2) * 128 + jj];
    float b = bnp[(t < 128 ? 1 : 3) * 128 + jj];
    float sc = g * rsqrtf(var + 1e-3f);
    scs[t] = sc; sbs[t] = b - mu * sc;
  }
  __syncthreads();
  float sc = scs[t], sh = sbs[t];
  for (int r = blockIdx.x; r < NN; r += gridDim.x){
    float v = h2f(Hp[(size_t)r * 256 + t]);
    if (t < 128) v = fmaxf(v, 0.f);
    OUT[(size_t)r * 256 + t] = f2h(v * sc + sh);
  }
}

// ---------------- fused layer-1 BN-apply + z = h1 @ We + be ----------------
__global__ void k_bnzdense(const unsigned short* __restrict__ Hp, const float* __restrict__ stats,
                           const float* __restrict__ bnp,
                           const float* __restrict__ We, const float* __restrict__ be,
                           float* __restrict__ Z){
  __shared__ float Hs[16 * 256];
  __shared__ float Ws[256 * 16];
  __shared__ float scs[256], sbs[256];
  int t = threadIdx.x;
  {
    const float invN = 1.f / (float)NN;
    float mu = stats[t] * invN;
    float var = stats[256 + t] * invN - mu * mu;
    int jj = (t < 128) ? t : t - 128;
    float g = bnp[(t < 128 ? 0 : 2) * 128 + jj];
    float b = bnp[(t < 128 ? 1 : 3) * 128 + jj];
    float sc = g * rsqrtf(var + 1e-3f);
    scs[t] = sc; sbs[t] = b - mu * sc;
  }
  __syncthreads();
  int r0 = blockIdx.x * 16;
  for (int i = t; i < 4096; i += 256){
    int col = i & 255;
    float v = h2f(Hp[(size_t)r0 * 256 + i]);
    if (col < 128) v = fmaxf(v, 0.f);
    Hs[i] = v * scs[col] + sbs[col];
    Ws[i] = We[i];
  }
  __syncthreads();
  int r = t >> 4, m = t & 15;
  float accv = be[m];
  const float* hrow = Hs + r * 256;
  #pragma unroll 8
  for (int k = 0; k < 256; k++) accv += hrow[k] * Ws[k * 16 + m];
  Z[(size_t)(r0 + r) * 16 + m] = accv;
}

// ---------------- per-edge softmax over 16 machines ----------------
__global__ void k_edge(const int* __restrict__ rows, const int* __restrict__ cols,
                       const float* __restrict__ vals, const float* __restrict__ Z,
                       float* __restrict__ out){
  int e = blockIdx.x * blockDim.x + threadIdx.x;
  if (e >= NE) return;
  int r = rows[e], c = cols[e];
  float v = vals[e];
  const float4* zr = (const float4*)(Z + (size_t)r * 16);
  const float4* zc = (const float4*)(Z + (size_t)c * 16);
  float s[16];
  #pragma unroll
  for (int q = 0; q < 4; q++){
    float4 a = zr[q], b = zc[q];
    s[q * 4 + 0] = v * (a.x + b.x);
    s[q * 4 + 1] = v * (a.y + b.y);
    s[q * 4 + 2] = v * (a.z + b.z);
    s[q * 4 + 3] = v * (a.w + b.w);
  }
  float mx = s[0];
  #pragma unroll
  for (int i = 1; i < 16; i++) mx = fmaxf(mx, s[i]);
  float sum = 0.f;
  #pragma unroll
  for (int i = 0; i < 16; i++){ s[i] = __expf(s[i] - mx); sum += s[i]; }
  float inv = 1.f / sum;
  float4* po = (float4*)(out + (size_t)e * 16);
  #pragma unroll
  for (int q = 0; q < 4; q++)
    po[q] = make_float4(s[q*4+0]*inv, s[q*4+1]*inv, s[q*4+2]*inv, s[q*4+3]*inv);
}

extern "C" void kernel_launch(void* const* d_in, const int* in_sizes, int n_in,
                              void* d_out, int out_size, void* d_ws, size_t ws_size,
                              hipStream_t stream){
  const float* x    = (const float*)d_in[0];
  const int* rows   = (const int*)d_in[1];
  const int* cols   = (const int*)d_in[2];
  const float* vals = (const float*)d_in[3];
  const float* l0Wa = (const float*)d_in[4];
  const float* l0Wb = (const float*)d_in[5];
  const float* l0bn = (const float*)d_in[6];
  const float* l1Wa = (const float*)d_in[7];
  const float* l1Wb = (const float*)d_in[8];
  const float* l1bn = (const float*)d_in[9];
  const float* We   = (const float*)d_in[10];
  const float* be   = (const float*)d_in[11];
  float* out        = (float*)d_out;

  uint8_t* p = (uint8_t*)d_ws;
  auto take = [&](size_t b) -> void* { void* q = (void*)p; p += (b + 255) & ~(size_t)255; return q; };
  int*   rowptr = (int*)take((size_t)(NN + 1) * 4);
  int*   cnt    = (int*)take((size_t)NN * 4);
  int*   fill   = (int*)take((size_t)NN * 4);
  int*   bsum   = (int*)take((size_t)SCANB * 4);
  int*   colss  = (int*)take((size_t)NE * 4);
  float* valss  = (float*)take((size_t)NE * 4);
  unsigned short* WT0 = (unsigned short*)take((size_t)256 * 512 * 2);
  unsigned short* WT1 = (unsigned short*)take((size_t)256 * 1024 * 2);
  float* stats  = (float*)take(512 * 4);
  float* Z      = (float*)take((size_t)NN * 16 * 4);
  unsigned short* Hp  = (unsigned short*)take((size_t)NN * 256 * 2);
  unsigned short* x16 = (unsigned short*)take((size_t)NN * 128 * 2);
  unsigned short* buf[5];
  for (int i = 0; i < 5; i++) buf[i] = (unsigned short*)take((size_t)NN * 256 * 2);

  // CSR build (workspace is poisoned every call — rebuild everything)
  hipMemsetAsync(cnt, 0, (size_t)NN * 4, stream);
  hipMemsetAsync(fill, 0, (size_t)NN * 4, stream);
  k_hist<<<NE / 256, 256, 0, stream>>>(rows, cnt);
  k_scan1<<<SCANB, 256, 0, stream>>>(cnt, rowptr, bsum);
  k_scan3<<<SCANB, 256, 0, stream>>>(rowptr, bsum);
  k_scatter<<<NE / 256, 256, 0, stream>>>(rows, cols, vals, rowptr, fill, colss, valss);
  k_buildWT<<<(256 * 512) / 256, 256, 0, stream>>>(l0Wa, l0Wb, WT0, 128);
  k_buildWT<<<(256 * 1024) / 256, 256, 0, stream>>>(l1Wa, l1Wb, WT1, 256);
  k_cast<<<(NN * 128 / 4 + 255) / 256, 256, 0, stream>>>(x, x16, NN * 128 / 4);

  dim3 gg(NP / 128, 2);

  // ---- layer 0 ----
  k_spmm<128><<<NN / 4, 256, 0, stream>>>(rowptr, colss, valss, x16,    buf[0]); // a0
  k_spmm<128><<<NN / 4, 256, 0, stream>>>(rowptr, colss, valss, buf[0], buf[1]); // a1
  k_spmm<128><<<NN / 4, 256, 0, stream>>>(rowptr, colss, valss, buf[1], buf[2]); // tmp = A a1
  k_spmm<128><<<NN / 4, 256, 0, stream>>>(rowptr, colss, valss, buf[2], buf[3]); // a2 = A tmp
  hipMemsetAsync(stats, 0, 512 * 4, stream);
  k_gemm4<128><<<gg, 256, 0, stream>>>(x16, buf[0], buf[1], buf[3], WT0, Hp, stats);
  k_bnapply<<<2048, 256, 0, stream>>>(Hp, stats, l0bn, buf[4]);                  // h0

  // ---- layer 1 ----
  k_spmm<256><<<NN / 4, 256, 0, stream>>>(rowptr, colss, valss, buf[4], buf[0]); // a0'
  k_spmm<256><<<NN / 4, 256, 0, stream>>>(rowptr, colss, valss, buf[0], buf[1]); // a1'
  k_spmm<256><<<NN / 4, 256, 0, stream>>>(rowptr, colss, valss, buf[1], buf[2]); // tmp'
  k_spmm<256><<<NN / 4, 256, 0, stream>>>(rowptr, colss, valss, buf[2], buf[3]); // a2'
  hipMemsetAsync(stats, 0, 512 * 4, stream);
  k_gemm4<256><<<gg, 256, 0, stream>>>(buf[4], buf[0], buf[1], buf[3], WT1, Hp, stats);
  k_bnzdense<<<NN / 16, 256, 0, stream>>>(Hp, stats, l1bn, We, be, Z);           // fused BN+zdense

  k_edge<<<NE / 256, 256, 0, stream>>>(rows, cols, vals, Z, out);
}